// Round 12
// baseline (842.136 us; speedup 1.0000x reference)
//
#include <hip/hip_runtime.h>
#include <math.h>

#define B_ROWS 8192
#define P_KEYS 2048
#define D_DIM  768
#define L_LEN  5
#define K_SEL  5
#define EPSV   1e-8f

#define RTILE 128
#define CTILE 128
#define KB 32
#define NCB (P_KEYS / CTILE)      // 16 column blocks

// sorted ascending (v[0] best). Tie-break: lower index wins (jax top_k semantics).
__device__ inline void insert5(float (&v)[K_SEL], int (&ix)[K_SEL], float nv, int ni) {
    if (nv < v[K_SEL-1] || (nv == v[K_SEL-1] && ni < ix[K_SEL-1])) {
        v[K_SEL-1] = nv; ix[K_SEL-1] = ni;
        #pragma unroll
        for (int j = K_SEL-1; j > 0; --j) {
            bool sw = (v[j] < v[j-1]) || (v[j] == v[j-1] && ix[j] < ix[j-1]);
            if (sw) {
                float tv = v[j]; v[j] = v[j-1]; v[j-1] = tv;
                int   ti = ix[j]; ix[j] = ix[j-1]; ix[j-1] = ti;
            }
        }
    }
}

// One wave (64 lanes) per row. waves [0, P_KEYS): normalize pool_key -> kn
// (pre-normalized B: GEMM numerics must match reference's x_hat . k_hat
// per-element rounding — r10's post-scale variant flipped a near-tied top-5).
// waves [P_KEYS, ...): x -> inv_x only.
__global__ __launch_bounds__(256)
void norm_kernel(const float* __restrict__ x, const float* __restrict__ pk,
                 float* __restrict__ kn, float* __restrict__ inv_x) {
    int wave = (blockIdx.x * blockDim.x + threadIdx.x) >> 6;
    int lane = threadIdx.x & 63;
    bool is_key = (wave < P_KEYS);
    int row = is_key ? wave : wave - P_KEYS;
    const float* src = is_key ? (pk + (size_t)row * D_DIM) : (x + (size_t)row * D_DIM);

    const float4* s4 = (const float4*)src;
    float4 v[3];
    float s = 0.f;
    #pragma unroll
    for (int i = 0; i < 3; ++i) {
        v[i] = s4[lane + 64 * i];
        s += v[i].x * v[i].x + v[i].y * v[i].y + v[i].z * v[i].z + v[i].w * v[i].w;
    }
    #pragma unroll
    for (int off = 32; off; off >>= 1) s += __shfl_xor(s, off, 64);
    float inv = 1.0f / fmaxf(sqrtf(s), EPSV);

    if (is_key) {
        float4* d4 = (float4*)(kn + (size_t)row * D_DIM);
        #pragma unroll
        for (int i = 0; i < 3; ++i) {
            float4 w = v[i];
            w.x *= inv; w.y *= inv; w.z *= inv; w.w *= inv;
            d4[lane + 64 * i] = w;
        }
    } else {
        if (lane == 0) inv_x[row] = inv;
    }
}

// Fused fp32 GEMM (dist = 1 - x_hat . k_hat) + per-row top-5 per 128-col block.
// B operands wave-uniform -> SGPR via scalar cache (zero DS/VMEM pipe cost);
// A through LDS.
//
// LDS LAYOUT (r11 post-mortem): stride-36 gave 8-way bank conflicts on
// ds_read_b128 (start-bank = lane*4 mod 32; 9.2M conflict cycles/dispatch,
// VALUBusy stuck at 46% = DS-pipe-bound). Now As[128][32] linear with
// XOR-swizzled col-quads: physical_quad = logical_quad ^ (row & 7).
//   read:  lanes 0..7 hit quads (2ch)^{0..7} -> all 8 bank-quads, conflict-free
//   write: 8-lane groups write quads sq^(sr&7) -> distinct, conflict-free
// Accumulation order identical to r11 (passed) — numerics unchanged.
// grid = (NCB, B_ROWS/RTILE), block = 1024 (16 waves).
__global__ __launch_bounds__(1024)
void gemm_top5_kernel(const float* __restrict__ x, const float* __restrict__ kn,
                      const float* __restrict__ inv_x,
                      float* __restrict__ cand_val, int* __restrict__ cand_idx) {
    const int cb   = blockIdx.x;
    const int rb   = blockIdx.y;
    const int row0 = rb * RTILE;
    const int tid  = threadIdx.x;
    const int lane = tid & 63;
    const int w    = __builtin_amdgcn_readfirstlane(tid >> 6);  // wave id 0..15 (uniform)
    const int col0w = cb * CTILE + w * 8;                        // this wave's 8 cols

    // 40 KB LDS, time-shared: phase 1 = As[128][32] (16 KB), phase 2 = merge
    __shared__ float smem[10240];
    float* As   = smem;
    float* mval = smem;                    // [row][8 slots][5]  = 5120 floats
    int*   midx = (int*)smem + 128 * 8 * K_SEL;

    // A staging: 1024 threads x 1 float4 = 128 rows x 32 k
    const int sr  = tid >> 3;              // 0..127
    const int sq  = tid & 7;               // col-quad 0..7
    const int skq = sq * 4;                // k offset in slab
    const int wq  = (sq ^ (sr & 7)) * 4;   // swizzled col within row
    const float iva = inv_x[row0 + sr];
    const float* ap = x + (size_t)(row0 + sr) * D_DIM + skq;

    const int swz = (lane & 7);            // read-side swizzle key (same for lane & lane+64)

    float acc[2][8] = {};

    float4 av = *(const float4*)ap;        // first slab
    for (int k0 = 0; k0 < D_DIM; k0 += KB) {
        __syncthreads();
        {
            float4 t = av;
            t.x *= iva; t.y *= iva; t.z *= iva; t.w *= iva;
            *(float4*)&As[sr * 32 + wq] = t;
        }
        __syncthreads();
        // prefetch next slab (latency hides under compute below)
        int knext = (k0 + KB < D_DIM) ? (k0 + KB) : 0;
        av = *(const float4*)(ap + knext);

        #pragma unroll
        for (int ch = 0; ch < 4; ++ch) {   // 8-k chunks
            const int q0 = ((2 * ch) ^ swz) * 4;
            const int q1 = ((2 * ch + 1) ^ swz) * 4;
            float4 a00 = *(const float4*)&As[lane * 32 + q0];
            float4 a01 = *(const float4*)&As[lane * 32 + q1];
            float4 a10 = *(const float4*)&As[(lane + 64) * 32 + q0];
            float4 a11 = *(const float4*)&As[(lane + 64) * 32 + q1];
            float a0[8] = {a00.x, a00.y, a00.z, a00.w, a01.x, a01.y, a01.z, a01.w};
            float a1[8] = {a10.x, a10.y, a10.z, a10.w, a11.x, a11.y, a11.z, a11.w};
            #pragma unroll
            for (int c = 0; c < 8; ++c) {
                // wave-uniform address -> scalar loads (SGPR b-operand in v_fma)
                const float* bp = kn + (size_t)(col0w + c) * D_DIM + k0 + ch * 8;
                #pragma unroll
                for (int j = 0; j < 8; ++j) {
                    float b = bp[j];
                    acc[0][c] += a0[j] * b;
                    acc[1][c] += a1[j] * b;
                }
            }
        }
    }

    // epilogue: dist = 1 - acc; per-lane top5 over this wave's 8 cols
    float tv0[K_SEL], tv1[K_SEL]; int ti0[K_SEL], ti1[K_SEL];
    #pragma unroll
    for (int j = 0; j < K_SEL; ++j) {
        tv0[j] = 3.0e38f; ti0[j] = 0x7fffffff;
        tv1[j] = 3.0e38f; ti1[j] = 0x7fffffff;
    }
    #pragma unroll
    for (int c = 0; c < 8; ++c) {
        insert5(tv0, ti0, 1.0f - acc[0][c], col0w + c);
        insert5(tv1, ti1, 1.0f - acc[1][c], col0w + c);
    }

    // two-stage in-block merge across the 16 waves (8 LDS slots)
    __syncthreads();   // As dead; reuse LDS
    if (w < 8) {
        #pragma unroll
        for (int j = 0; j < K_SEL; ++j) {
            mval[(lane * 8 + w) * K_SEL + j] = tv0[j];
            midx[(lane * 8 + w) * K_SEL + j] = ti0[j];
            mval[((lane + 64) * 8 + w) * K_SEL + j] = tv1[j];
            midx[((lane + 64) * 8 + w) * K_SEL + j] = ti1[j];
        }
    }
    __syncthreads();
    if (w >= 8) {
        int s = w - 8;
        #pragma unroll
        for (int j = 0; j < K_SEL; ++j)
            insert5(tv0, ti0, mval[(lane * 8 + s) * K_SEL + j], midx[(lane * 8 + s) * K_SEL + j]);
        #pragma unroll
        for (int j = 0; j < K_SEL; ++j)
            insert5(tv1, ti1, mval[((lane + 64) * 8 + s) * K_SEL + j], midx[((lane + 64) * 8 + s) * K_SEL + j]);
        #pragma unroll
        for (int j = 0; j < K_SEL; ++j) {
            mval[(lane * 8 + s) * K_SEL + j] = tv0[j];
            midx[(lane * 8 + s) * K_SEL + j] = ti0[j];
            mval[((lane + 64) * 8 + s) * K_SEL + j] = tv1[j];
            midx[((lane + 64) * 8 + s) * K_SEL + j] = ti1[j];
        }
    }
    __syncthreads();
    if (tid < RTILE) {
        float fv[K_SEL]; int fi[K_SEL];
        #pragma unroll
        for (int j = 0; j < K_SEL; ++j) { fv[j] = 3.0e38f; fi[j] = 0x7fffffff; }
        for (int s = 0; s < 8; ++s)
            #pragma unroll
            for (int j = 0; j < K_SEL; ++j)
                insert5(fv, fi, mval[(tid * 8 + s) * K_SEL + j], midx[(tid * 8 + s) * K_SEL + j]);
        int grow = row0 + tid;
        #pragma unroll
        for (int j = 0; j < K_SEL; ++j) {
            cand_val[((size_t)grow * NCB + cb) * K_SEL + j] = fv[j];
            cand_idx[((size_t)grow * NCB + cb) * K_SEL + j] = fi[j];
        }
    }
}

__global__ __launch_bounds__(256)
void merge_kernel(const float* __restrict__ cand_val, const int* __restrict__ cand_idx,
                  float* __restrict__ out_dist, int* __restrict__ final_idx) {
    int row = blockIdx.x * blockDim.x + threadIdx.x;
    if (row >= B_ROWS) return;
    float fv[K_SEL]; int fi[K_SEL];
    #pragma unroll
    for (int j = 0; j < K_SEL; ++j) { fv[j] = 3.0e38f; fi[j] = 0x7fffffff; }
    for (int t = 0; t < NCB * K_SEL; ++t)
        insert5(fv, fi, cand_val[(size_t)row * NCB * K_SEL + t],
                        cand_idx[(size_t)row * NCB * K_SEL + t]);
    #pragma unroll
    for (int j = 0; j < K_SEL; ++j) {
        out_dist[(size_t)row * K_SEL + j] = fv[j];
        final_idx[(size_t)row * K_SEL + j] = fi[j];
    }
}

// one block per (b, s): copy prompts[idx] (5*768 floats = 960 float4) to output
__global__ __launch_bounds__(256)
void gather_kernel(const float* __restrict__ prompts, const int* __restrict__ final_idx,
                   float* __restrict__ out1) {
    int bs = blockIdx.x;                 // 0 .. B_ROWS*K_SEL-1
    int p = final_idx[bs];
    const float4* src = (const float4*)(prompts + (size_t)p * (L_LEN * D_DIM));
    float4* dst = (float4*)(out1 + (size_t)bs * (L_LEN * D_DIM));
    const int n4 = (L_LEN * D_DIM) / 4;  // 960
    for (int i = threadIdx.x; i < n4; i += blockDim.x) dst[i] = src[i];
}

extern "C" void kernel_launch(void* const* d_in, const int* in_sizes, int n_in,
                              void* d_out, int out_size, void* d_ws, size_t ws_size,
                              hipStream_t stream) {
    const float* x       = (const float*)d_in[0];   // [8192, 768]
    const float* pk      = (const float*)d_in[1];   // [2048, 768]
    const float* prompts = (const float*)d_in[2];   // [2048, 5, 768]

    float* out_dist = (float*)d_out;                          // [8192, 5]
    float* out_pr   = (float*)d_out + (size_t)B_ROWS * K_SEL; // [8192, 5, 5, 768]

    char* ws = (char*)d_ws;
    float* kn       = (float*)(ws);                              // 6,291,456 B
    float* inv_x    = (float*)(ws + 6291456);                    //    32,768 B
    float* cand_val = (float*)(ws + 6291456 + 32768);            // 2,621,440 B
    int*   cand_idx = (int*)  (ws + 6291456 + 32768 + 2621440);  // 2,621,440 B
    int*   final_ix = (int*)  (ws + 6291456 + 32768 + 2*2621440);//   163,840 B

    // 1) normalize keys -> kn; inverse norms for x
    norm_kernel<<<(P_KEYS + B_ROWS) / 4, 256, 0, stream>>>(x, pk, kn, inv_x);
    // 2) fused GEMM (SGPR-B from kn / swizzled-LDS-A) + per-colblock top5
    {
        dim3 grid(NCB, B_ROWS / RTILE);
        gemm_top5_kernel<<<grid, 1024, 0, stream>>>(x, kn, inv_x, cand_val, cand_idx);
    }
    // 3) cross-colblock merge
    merge_kernel<<<B_ROWS / 256, 256, 0, stream>>>(cand_val, cand_idx, out_dist, final_ix);
    // 4) gather prompts
    gather_kernel<<<B_ROWS * K_SEL, 256, 0, stream>>>(prompts, final_ix, out_pr);
}

// Round 14
// 637.339 us; speedup vs baseline: 1.3213x; 1.3213x over previous
//
#include <hip/hip_runtime.h>
#include <math.h>

#define B_ROWS 8192
#define P_KEYS 2048
#define D_DIM  768
#define L_LEN  5
#define K_SEL  5
#define EPSV   1e-8f

#define RTILE 256
#define CTILE 64
#define KB 32
#define NCB (P_KEYS / CTILE)      // 32 column blocks

// sorted ascending (v[0] best). Tie-break: lower index wins (jax top_k semantics).
__device__ inline void insert5(float (&v)[K_SEL], int (&ix)[K_SEL], float nv, int ni) {
    if (nv < v[K_SEL-1] || (nv == v[K_SEL-1] && ni < ix[K_SEL-1])) {
        v[K_SEL-1] = nv; ix[K_SEL-1] = ni;
        #pragma unroll
        for (int j = K_SEL-1; j > 0; --j) {
            bool sw = (v[j] < v[j-1]) || (v[j] == v[j-1] && ix[j] < ix[j-1]);
            if (sw) {
                float tv = v[j]; v[j] = v[j-1]; v[j-1] = tv;
                int   ti = ix[j]; ix[j] = ix[j-1]; ix[j-1] = ti;
            }
        }
    }
}

// One wave (64 lanes) per row. waves [0, P_KEYS): normalize pool_key -> kn
// (pre-normalized B: GEMM numerics must match reference's x_hat . k_hat
// per-element rounding — r10's post-scale variant flipped a near-tied top-5).
// waves [P_KEYS, ...): x -> inv_x only.
__global__ __launch_bounds__(256)
void norm_kernel(const float* __restrict__ x, const float* __restrict__ pk,
                 float* __restrict__ kn, float* __restrict__ inv_x) {
    int wave = (blockIdx.x * blockDim.x + threadIdx.x) >> 6;
    int lane = threadIdx.x & 63;
    bool is_key = (wave < P_KEYS);
    int row = is_key ? wave : wave - P_KEYS;
    const float* src = is_key ? (pk + (size_t)row * D_DIM) : (x + (size_t)row * D_DIM);

    const float4* s4 = (const float4*)src;
    float4 v[3];
    float s = 0.f;
    #pragma unroll
    for (int i = 0; i < 3; ++i) {
        v[i] = s4[lane + 64 * i];
        s += v[i].x * v[i].x + v[i].y * v[i].y + v[i].z * v[i].z + v[i].w * v[i].w;
    }
    #pragma unroll
    for (int off = 32; off; off >>= 1) s += __shfl_xor(s, off, 64);
    float inv = 1.0f / fmaxf(sqrtf(s), EPSV);

    if (is_key) {
        float4* d4 = (float4*)(kn + (size_t)row * D_DIM);
        #pragma unroll
        for (int i = 0; i < 3; ++i) {
            float4 w = v[i];
            w.x *= inv; w.y *= inv; w.z *= inv; w.w *= inv;
            d4[lane + 64 * i] = w;
        }
    } else {
        if (lane == 0) inv_x[row] = inv;
    }
}

// Fused fp32 GEMM (dist = 1 - x_hat . k_hat) + per-row top-5 per 64-col block.
// B wave-uniform -> s_load (SGPR_Count 112 in r11/r12 proves scalarization).
// r12 A/B showed bank conflicts are irrelevant (9M vs 34M conflicts, identical
// 685 us, VALU 46%): the limiter is the s_load latency chain (~32 scalar-cache
// -missing batches/slab, only 4 waves/SIMD to hide). This round: 4 ROWS PER
// LANE -> each b value feeds 4 FMAs (2x the scalar-load reuse of r11/r12).
// grid = (NCB, B_ROWS/RTILE) = (32, 32), block = 512 (8 waves x 8 cols).
// Lane owns rows {l, l+64, l+128, l+192}; acc[4][8]; VGPR ~95 (watch spill).
__global__ __launch_bounds__(512)
void gemm_top5_kernel(const float* __restrict__ x, const float* __restrict__ kn,
                      const float* __restrict__ inv_x,
                      float* __restrict__ cand_val, int* __restrict__ cand_idx) {
    const int cb   = blockIdx.x;
    const int rb   = blockIdx.y;
    const int row0 = rb * RTILE;
    const int tid  = threadIdx.x;
    const int lane = tid & 63;
    const int w    = __builtin_amdgcn_readfirstlane(tid >> 6);  // wave id 0..7
    const int col0w = cb * CTILE + w * 8;                        // this wave's 8 cols

    // 40 KB LDS, time-shared: phase 1 = As[256][32] (32 KB), phase 2 = merge
    __shared__ float smem[10240];
    float* As   = smem;
    float* mval = smem;                    // [256 rows][4 slots][5]
    int*   midx = (int*)smem + 256 * 4 * K_SEL;   // after 5120 floats

    // A staging: 512 threads x 4 float4 = 256 rows x 32 k
    const int sr = tid >> 3;               // 0..63
    const int sq = tid & 7;                // col-quad
    const int wq = (sq ^ (sr & 7)) * 4;    // swizzled (row&7 same for all 4 rows)
    const float* ap0 = x + (size_t)(row0 + sr) * D_DIM + sq * 4;
    float iva[4];
    #pragma unroll
    for (int m = 0; m < 4; ++m) iva[m] = inv_x[row0 + sr + 64 * m];

    const int swz = lane & 7;
    float acc[4][8] = {};

    float4 pf[4];
    #pragma unroll
    for (int m = 0; m < 4; ++m)
        pf[m] = *(const float4*)(ap0 + (size_t)m * 64 * D_DIM);

    for (int k0 = 0; k0 < D_DIM; k0 += KB) {
        __syncthreads();
        #pragma unroll
        for (int m = 0; m < 4; ++m) {
            float4 t = pf[m];
            t.x *= iva[m]; t.y *= iva[m]; t.z *= iva[m]; t.w *= iva[m];
            *(float4*)&As[(sr + 64 * m) * 32 + wq] = t;
        }
        __syncthreads();
        int knext = (k0 + KB < D_DIM) ? (k0 + KB) : 0;
        #pragma unroll
        for (int m = 0; m < 4; ++m)
            pf[m] = *(const float4*)(ap0 + (size_t)m * 64 * D_DIM + knext);

        #pragma unroll
        for (int ch = 0; ch < 4; ++ch) {   // 8-k chunks
            const int q0 = ((2 * ch) ^ swz) * 4;
            const int q1 = ((2 * ch + 1) ^ swz) * 4;
            float a[4][8];
            #pragma unroll
            for (int m = 0; m < 4; ++m) {
                float4 lo = *(const float4*)&As[(lane + 64 * m) * 32 + q0];
                float4 hi = *(const float4*)&As[(lane + 64 * m) * 32 + q1];
                a[m][0] = lo.x; a[m][1] = lo.y; a[m][2] = lo.z; a[m][3] = lo.w;
                a[m][4] = hi.x; a[m][5] = hi.y; a[m][6] = hi.z; a[m][7] = hi.w;
            }
            #pragma unroll
            for (int c = 0; c < 8; ++c) {
                // wave-uniform address -> s_load (SGPR b-operand in v_fma)
                const float* bp = kn + (size_t)(col0w + c) * D_DIM + k0 + ch * 8;
                #pragma unroll
                for (int j = 0; j < 8; ++j) {
                    float b = bp[j];
                    #pragma unroll
                    for (int m = 0; m < 4; ++m)
                        acc[m][c] += a[m][j] * b;
                }
            }
        }
    }

    // epilogue: per-lane top5 per row over this wave's 8 cols
    float tv[4][K_SEL]; int ti[4][K_SEL];
    #pragma unroll
    for (int m = 0; m < 4; ++m)
        #pragma unroll
        for (int j = 0; j < K_SEL; ++j) { tv[m][j] = 3.0e38f; ti[m][j] = 0x7fffffff; }
    #pragma unroll
    for (int m = 0; m < 4; ++m)
        #pragma unroll
        for (int c = 0; c < 8; ++c)
            insert5(tv[m], ti[m], 1.0f - acc[m][c], col0w + c);

    // pairwise wave-tree merge: 4-7 -> 0-3, 2-3 -> 0-1, 1 -> 0 (slots 0..3)
    #pragma unroll
    for (int hb = 4; hb >= 1; hb >>= 1) {
        __syncthreads();
        if (w >= hb && w < 2 * hb) {
            int s = w - hb;
            #pragma unroll
            for (int m = 0; m < 4; ++m)
                #pragma unroll
                for (int j = 0; j < K_SEL; ++j) {
                    mval[((lane + 64 * m) * 4 + s) * K_SEL + j] = tv[m][j];
                    midx[((lane + 64 * m) * 4 + s) * K_SEL + j] = ti[m][j];
                }
        }
        __syncthreads();
        if (w < hb) {
            #pragma unroll
            for (int m = 0; m < 4; ++m)
                #pragma unroll
                for (int j = 0; j < K_SEL; ++j)
                    insert5(tv[m], ti[m],
                            mval[((lane + 64 * m) * 4 + w) * K_SEL + j],
                            midx[((lane + 64 * m) * 4 + w) * K_SEL + j]);
        }
    }

    if (w == 0) {
        #pragma unroll
        for (int m = 0; m < 4; ++m) {
            int grow = row0 + lane + 64 * m;
            #pragma unroll
            for (int j = 0; j < K_SEL; ++j) {
                cand_val[((size_t)grow * NCB + cb) * K_SEL + j] = tv[m][j];
                cand_idx[((size_t)grow * NCB + cb) * K_SEL + j] = ti[m][j];
            }
        }
    }
}

__global__ __launch_bounds__(256)
void merge_kernel(const float* __restrict__ cand_val, const int* __restrict__ cand_idx,
                  float* __restrict__ out_dist, int* __restrict__ final_idx) {
    int row = blockIdx.x * blockDim.x + threadIdx.x;
    if (row >= B_ROWS) return;
    float fv[K_SEL]; int fi[K_SEL];
    #pragma unroll
    for (int j = 0; j < K_SEL; ++j) { fv[j] = 3.0e38f; fi[j] = 0x7fffffff; }
    for (int t = 0; t < NCB * K_SEL; ++t)
        insert5(fv, fi, cand_val[(size_t)row * NCB * K_SEL + t],
                        cand_idx[(size_t)row * NCB * K_SEL + t]);
    #pragma unroll
    for (int j = 0; j < K_SEL; ++j) {
        out_dist[(size_t)row * K_SEL + j] = fv[j];
        final_idx[(size_t)row * K_SEL + j] = fi[j];
    }
}

// one block per (b, s): copy prompts[idx] (5*768 floats = 960 float4) to output
__global__ __launch_bounds__(256)
void gather_kernel(const float* __restrict__ prompts, const int* __restrict__ final_idx,
                   float* __restrict__ out1) {
    int bs = blockIdx.x;                 // 0 .. B_ROWS*K_SEL-1
    int p = final_idx[bs];
    const float4* src = (const float4*)(prompts + (size_t)p * (L_LEN * D_DIM));
    float4* dst = (float4*)(out1 + (size_t)bs * (L_LEN * D_DIM));
    const int n4 = (L_LEN * D_DIM) / 4;  // 960
    for (int i = threadIdx.x; i < n4; i += blockDim.x) dst[i] = src[i];
}

extern "C" void kernel_launch(void* const* d_in, const int* in_sizes, int n_in,
                              void* d_out, int out_size, void* d_ws, size_t ws_size,
                              hipStream_t stream) {
    const float* x       = (const float*)d_in[0];   // [8192, 768]
    const float* pk      = (const float*)d_in[1];   // [2048, 768]
    const float* prompts = (const float*)d_in[2];   // [2048, 5, 768]

    float* out_dist = (float*)d_out;                          // [8192, 5]
    float* out_pr   = (float*)d_out + (size_t)B_ROWS * K_SEL; // [8192, 5, 5, 768]

    char* ws = (char*)d_ws;
    float* kn       = (float*)(ws);                               // 6,291,456 B
    float* inv_x    = (float*)(ws + 6291456);                     //    32,768 B
    float* cand_val = (float*)(ws + 6324224);                     // 5,242,880 B
    int*   cand_idx = (int*)  (ws + 6324224 + 5242880);           // 5,242,880 B
    int*   final_ix = (int*)  (ws + 6324224 + 2*5242880);         //   163,840 B

    // 1) normalize keys -> kn; inverse norms for x
    norm_kernel<<<(P_KEYS + B_ROWS) / 4, 256, 0, stream>>>(x, pk, kn, inv_x);
    // 2) fused GEMM (SGPR-B from kn / LDS-A, 4 rows/lane) + per-colblock top5
    {
        dim3 grid(NCB, B_ROWS / RTILE);
        gemm_top5_kernel<<<grid, 512, 0, stream>>>(x, kn, inv_x, cand_val, cand_idx);
    }
    // 3) cross-colblock merge
    merge_kernel<<<B_ROWS / 256, 256, 0, stream>>>(cand_val, cand_idx, out_dist, final_ix);
    // 4) gather prompts
    gather_kernel<<<B_ROWS * K_SEL, 256, 0, stream>>>(prompts, final_ix, out_pr);
}